// Round 5
// baseline (661.547 us; speedup 1.0000x reference)
//
#include <hip/hip_runtime.h>
#include <cstddef>
#include <cstdint>

// Bigram CE via MFMA, operand-swapped: D = W_tile · emb_tile^T so each lane's
// 4 accumulator values are 4 CONSECUTIVE vocab columns of one seq row ->
// direct dwordx4 stores from the accumulator. No LDS transpose, no in-loop
// barriers, no global atomics. fp32 via bf16 hi/lo split (3 MFMAs).
// N=4096 rows, V=100277, K=32.

using f32x4  = __attribute__((ext_vector_type(4))) float;
using bf16x8 = __attribute__((ext_vector_type(8))) __bf16;

static __device__ __forceinline__ unsigned short f2bf_rne(float f) {
    unsigned u = __float_as_uint(f);
    unsigned r = u + 0x7FFFu + ((u >> 16) & 1u);
    return (unsigned short)(r >> 16);
}
static __device__ __forceinline__ float bf2f(unsigned short h) {
    return __uint_as_float(((unsigned)h) << 16);
}
static __device__ __forceinline__ uint4 pack8(const unsigned short* h) {
    uint4 u;
    u.x = (unsigned)h[0] | ((unsigned)h[1] << 16);
    u.y = (unsigned)h[2] | ((unsigned)h[3] << 16);
    u.z = (unsigned)h[4] | ((unsigned)h[5] << 16);
    u.w = (unsigned)h[6] | ((unsigned)h[7] << 16);
    return u;
}

constexpr int N_ROWS = 4096;
constexpr int CHUNKS = N_ROWS / 16;                    // 256 row-chunks of 16
constexpr int TILES  = 4;                              // 16-col tiles per wave
constexpr int WAVES_PB = 4;
constexpr int V_PER_BLOCK = WAVES_PB * TILES * 16;     // 256 cols per block
constexpr int ROW_SPLITS = 8;
constexpr int CHUNKS_PER_SPLIT = CHUNKS / ROW_SPLITS;  // 32
constexpr int ROWS_PER_BLOCK = CHUNKS_PER_SPLIT * 16;  // 512
constexpr int NCOLB = (100277 + V_PER_BLOCK - 1) / V_PER_BLOCK;  // 392

// d_ws layout (bytes)
constexpr size_t RS_OFF   = 0;                          // rowsum: 4096 f32
constexpr size_t A_HI_OFF = 16384;
constexpr size_t A_BYTES  = (size_t)CHUNKS * 64 * 16;   // 256 KB
constexpr size_t A_LO_OFF = A_HI_OFF + A_BYTES;
constexpr size_t PART_OFF = A_LO_OFF + A_BYTES;         // NCOLB*4096 f32 = 6.4 MB

// Pack E = emb[seq] into MFMA fragment order (second operand), hi/lo bf16.
// Lane l -> n = l&15 (seq row within chunk), k = (l>>4)*8 .. +7 contiguous.
__global__ __launch_bounds__(256) void prep_afrag(
    const int*   __restrict__ seq,
    const float* __restrict__ emb,
    uint4*       __restrict__ a_hi,
    uint4*       __restrict__ a_lo)
{
    const int g   = blockIdx.x * 256 + threadIdx.x;    // 16384 = CHUNKS*64
    const int l   = g & 63;
    const int c   = g >> 6;
    const int row = c * 16 + (l & 15);
    const int k0  = (l >> 4) * 8;
    const int idx = seq[row];

    const float* ep = emb + (size_t)idx * 32 + k0;
    float f[8];
    *reinterpret_cast<float4*>(f)     = *reinterpret_cast<const float4*>(ep);
    *reinterpret_cast<float4*>(f + 4) = *reinterpret_cast<const float4*>(ep + 4);

    unsigned short hs[8], ls[8];
#pragma unroll
    for (int i = 0; i < 8; ++i) {
        hs[i] = f2bf_rne(f[i]);
        ls[i] = f2bf_rne(f[i] - bf2f(hs[i]));
    }
    a_hi[g] = pack8(hs);
    a_lo[g] = pack8(ls);
}

__global__ __launch_bounds__(256) void bigram_mfma(
    const float* __restrict__ W,
    const float* __restrict__ bias,
    const uint4* __restrict__ a_hi,
    const uint4* __restrict__ a_lo,
    float*       __restrict__ logits,
    float*       __restrict__ part,     // [NCOLB][4096]
    int V)
{
    __shared__ float lsum[WAVES_PB][ROWS_PER_BLOCK];   // wave-private slices, 8 KB

    const int tid   = threadIdx.x;
    const int lane  = tid & 63;
    const int wid   = tid >> 6;
    const int colb  = blockIdx.x >> 3;                 // 0..391
    const int rsp   = blockIdx.x & 7;                  // 0..7
    const int lgrp  = lane >> 4;                       // 0..3
    const int lcol  = lane & 15;
    const int k0    = lgrp * 8;

    const int  cbase = colb * V_PER_BLOCK + wid * (TILES * 16);  // wave's first col
    const bool tail  = (colb == NCOLB - 1);            // uniform: only last block

    // Zero this wave's private lsum slice (no cross-wave touch -> no barrier).
#pragma unroll
    for (int i = 0; i < ROWS_PER_BLOCK / 64; ++i)
        lsum[wid][i * 64 + lane] = 0.f;

    // W fragments (FIRST MFMA operand): lane l -> m = l&15 -> col = cbase+t*16+lcol,
    // k = k0..k0+7 contiguous (W row-major [V][32]). hi/lo bf16 split.
    bf16x8 whi[TILES], wlo[TILES];
    f32x4  binit[TILES];           // bias C-init, indexed by store-side cols
#pragma unroll
    for (int t = 0; t < TILES; ++t) {
        const int colf = cbase + t * 16 + lcol;
        const int cc   = colf < V ? colf : V - 1;
        const float* wp = W + (size_t)cc * 32 + k0;
        float f[8];
        *reinterpret_cast<float4*>(f)     = *reinterpret_cast<const float4*>(wp);
        *reinterpret_cast<float4*>(f + 4) = *reinterpret_cast<const float4*>(wp + 4);
        unsigned short hs[8], ls[8];
#pragma unroll
        for (int i = 0; i < 8; ++i) {
            hs[i] = f2bf_rne(f[i]);
            ls[i] = f2bf_rne(f[i] - bf2f(hs[i]));
        }
        const uint4 H = pack8(hs), L = pack8(ls);
        whi[t] = __builtin_bit_cast(bf16x8, H);
        wlo[t] = __builtin_bit_cast(bf16x8, L);

        const int c0 = cbase + t * 16 + lgrp * 4;      // store-side col base
        if (!tail) {
            const float4 b4 = *reinterpret_cast<const float4*>(bias + c0);
            binit[t] = f32x4{b4.x, b4.y, b4.z, b4.w};
        } else {
#pragma unroll
            for (int j = 0; j < 4; ++j) {
                const int c = c0 + j;
                binit[t][j] = bias[c < V ? c : V - 1];
            }
        }
    }

    const int c_begin = rsp * CHUNKS_PER_SPLIT;

    // Prefetch first chunk's emb fragments.
    uint4 AH = a_hi[c_begin * 64 + lane];
    uint4 AL = a_lo[c_begin * 64 + lane];

    for (int c = c_begin; c < c_begin + CHUNKS_PER_SPLIT; ++c) {
        // Prefetch next chunk (clamped) — hides L2 latency under MFMA+exp.
        const int cn = (c + 1 < c_begin + CHUNKS_PER_SPLIT) ? c + 1 : c;
        const uint4 AHn = a_hi[cn * 64 + lane];
        const uint4 ALn = a_lo[cn * 64 + lane];

        const bf16x8 eh = __builtin_bit_cast(bf16x8, AH);
        const bf16x8 el = __builtin_bit_cast(bf16x8, AL);

        f32x4 acc[TILES];
#pragma unroll
        for (int t = 0; t < TILES; ++t) {
            f32x4 a0 = binit[t];
            a0 = __builtin_amdgcn_mfma_f32_16x16x32_bf16(whi[t], eh, a0, 0, 0, 0);
            a0 = __builtin_amdgcn_mfma_f32_16x16x32_bf16(wlo[t], eh, a0, 0, 0, 0);
            a0 = __builtin_amdgcn_mfma_f32_16x16x32_bf16(whi[t], el, a0, 0, 0, 0);
            acc[t] = a0;
        }

        // D layout (operand-swapped): n = lane&15 (seq row), m = (lane>>4)*4+j
        // (vocab col) -> lane's float4 = 4 consecutive vocab cols of row n.
        const int n = c * 16 + lcol;
        float* rowp = logits + (size_t)n * V;
        float s = 0.f;
#pragma unroll
        for (int t = 0; t < TILES; ++t) {
            const int c0 = cbase + t * 16 + lgrp * 4;
            if (!tail) {
                *reinterpret_cast<f32x4*>(rowp + c0) = acc[t];
                s += __expf(acc[t][0]) + __expf(acc[t][1]) +
                     __expf(acc[t][2]) + __expf(acc[t][3]);
            } else {
#pragma unroll
                for (int j = 0; j < 4; ++j) {
                    if (c0 + j < V) {
                        rowp[c0 + j] = acc[t][j];
                        s += __expf(acc[t][j]);
                    }
                }
            }
        }
        // Row-partial: reduce over the 4 lanes sharing this row (lane ^16, ^32).
        s += __shfl_xor(s, 16, 64);
        s += __shfl_xor(s, 32, 64);
        if (lane < 16)
            lsum[wid][(c - c_begin) * 16 + lane] += s;

        AH = AHn; AL = ALn;
    }

    __syncthreads();   // the only barrier: combine the 4 wave slices
    for (int r = tid; r < ROWS_PER_BLOCK; r += 256) {
        part[(size_t)colb * N_ROWS + rsp * ROWS_PER_BLOCK + r] =
            lsum[0][r] + lsum[1][r] + lsum[2][r] + lsum[3][r];
    }
}

// rowsum[n] = sum over column blocks of part[cb][n]  (coalesced across threads)
__global__ __launch_bounds__(256) void reduce_rowsum(
    const float* __restrict__ part,
    float*       __restrict__ rowsum,
    int nColBlocks, int N)
{
    const int n = blockIdx.x * 256 + threadIdx.x;
    if (n >= N) return;
    float s = 0.f;
#pragma unroll 4
    for (int p = 0; p < nColBlocks; ++p) s += part[(size_t)p * N + n];
    rowsum[n] = s;
}

// loss = mean( log(rowsum[n]) - (dot(emb[seq[n]], W[pred[n]]) + b[pred[n]]) )
__global__ void bigram_loss(
    const int*   __restrict__ seq,
    const int*   __restrict__ pred,
    const float* __restrict__ emb,
    const float* __restrict__ W,
    const float* __restrict__ bias,
    const float* __restrict__ rowsum,
    float*       __restrict__ loss,
    int N)
{
    const int tid = threadIdx.x;
    float local = 0.f;
    for (int n = blockIdx.x * blockDim.x + tid; n < N; n += gridDim.x * blockDim.x) {
        const int r = seq[n], t = pred[n];
        const float4* e4 = reinterpret_cast<const float4*>(emb + (size_t)r * 32);
        const float4* w4 = reinterpret_cast<const float4*>(W + (size_t)t * 32);
        float d = bias[t];
#pragma unroll
        for (int i = 0; i < 8; ++i) {
            const float4 e = e4[i], w = w4[i];
            d += e.x * w.x + e.y * w.y + e.z * w.z + e.w * w.w;
        }
        local += __logf(rowsum[n]) - d;
    }
#pragma unroll
    for (int off = 32; off >= 1; off >>= 1) local += __shfl_xor(local, off, 64);
    __shared__ float r4[4];
    if ((tid & 63) == 0) r4[tid >> 6] = local;
    __syncthreads();
    if (tid == 0) {
        const float s = r4[0] + r4[1] + r4[2] + r4[3];
        atomicAdd(loss, s / (float)N);
    }
}

extern "C" void kernel_launch(void* const* d_in, const int* in_sizes, int n_in,
                              void* d_out, int out_size, void* d_ws, size_t ws_size,
                              hipStream_t stream)
{
    const int*   seq  = (const int*)d_in[0];
    const int*   pred = (const int*)d_in[1];
    const float* emb  = (const float*)d_in[2];
    const float* W    = (const float*)d_in[3];
    const float* bias = (const float*)d_in[4];

    const int N = in_sizes[0];      // 4096
    const int V = in_sizes[4];      // 100277

    float* logits = (float*)d_out;
    float* loss   = logits + (size_t)N * V;

    char*  ws     = (char*)d_ws;
    float* rowsum = (float*)(ws + RS_OFF);
    uint4* a_hi   = (uint4*)(ws + A_HI_OFF);
    uint4* a_lo   = (uint4*)(ws + A_LO_OFF);
    float* part   = (float*)(ws + PART_OFF);

    hipMemsetAsync((void*)loss, 0, sizeof(float), stream);

    hipLaunchKernelGGL(prep_afrag, dim3(CHUNKS * 64 / 256), dim3(256), 0, stream,
                       seq, emb, a_hi, a_lo);

    hipLaunchKernelGGL(bigram_mfma, dim3(NCOLB * ROW_SPLITS), dim3(256), 0, stream,
                       W, bias, a_hi, a_lo, logits, part, V);

    hipLaunchKernelGGL(reduce_rowsum, dim3((N + 255) / 256), dim3(256), 0, stream,
                       part, rowsum, NCOLB, N);

    hipLaunchKernelGGL(bigram_loss, dim3(16), dim3(256), 0, stream,
                       seq, pred, emb, W, bias, rowsum, loss, N);
}